// Round 11
// baseline (231.115 us; speedup 1.0000x reference)
//
#include <hip/hip_runtime.h>
#include <hip/hip_fp16.h>

// DilatedReparamBlock folded into one 13x13 depthwise conv + bias.
//
// R14: cut the VALU floor with v_dot2_f32_f16. Cross-round invariants:
// VALUBusy*dur = 73-74 us in R7/R12/R13 (VALU work constant); occupancy
// pinned ~6 waves/CU regardless of LDS/block shape (3 failed attacks);
// LDS throughput non-binding (R7 -33% reads -> -12% dur; R12 -50% traffic
// -> +10% dur). Regime: latency-exposed around a 60 us VALU floor.
//  - x staged fp16 (R12 layout, 3 b128/row) AND weights packed fp16 pairs;
//    inner loop = 7 dot2 per (ky,row,col) (w[13]=0 pad) -> MAC instr
//    9464 -> 5096/lane; no cvt chain (dot2 eats packed halves directly).
//  - odd output cols use v_alignbit-built shifted pairs (10/row).
//  - per-ky-group weights = 28 u32 -> SGPRs via readfirstlane.
//  - f32 accumulate inside dot2 => only input quantization added; x-fp16
//    proven at absmax 0.03125 (passed); __has_builtin fallback to cvt+fma.

#define CCH 384
#define SP 56
#define PWH 72             // halves per padded row (16B-aligned lane bases)
#define NPLANES (16*384)

typedef __attribute__((ext_vector_type(4))) unsigned int u32x4;
typedef _Float16 hf2 __attribute__((ext_vector_type(2)));

__device__ __forceinline__ float rfl(float v) {
    return __int_as_float(__builtin_amdgcn_readfirstlane(__float_as_int(v)));
}
__device__ __forceinline__ unsigned rflu(unsigned v) {
    return (unsigned)__builtin_amdgcn_readfirstlane((int)v);
}
__device__ __forceinline__ hf2 as_hf2(unsigned v) {
    union { unsigned u; hf2 h; } x; x.u = v; return x.h;
}
__device__ __forceinline__ float dot2h(float c, unsigned x, unsigned w) {
#if __has_builtin(__builtin_amdgcn_fdot2)
    return __builtin_amdgcn_fdot2(as_hf2(x), as_hf2(w), c, false);
#else
    hf2 xh = as_hf2(x), wh = as_hf2(w);
    return fmaf((float)xh.x, (float)wh.x, fmaf((float)xh.y, (float)wh.y, c));
#endif
}

__global__ __launch_bounds__(64, 2) void drb_conv13_r14(
    const float* __restrict__ x,
    const float* __restrict__ w_lk, const float* __restrict__ w_b0,
    const float* __restrict__ w_b1, const float* __restrict__ w_b2,
    const float* __restrict__ w_b3, const float* __restrict__ w_b4,
    const float* __restrict__ w_b5,
    const float* __restrict__ gamma, const float* __restrict__ beta,
    const float* __restrict__ mean, const float* __restrict__ var,
    float* __restrict__ out)
{
    __shared__ __align__(16) __half sxh[68 * PWH];    // 9792 B fp16 plane
    __shared__ __align__(16) float sw[13 * 16];       // merged weights, f32
    __shared__ __align__(16) unsigned swh[13 * 8];    // packed half2 pairs

    const int plane = blockIdx.x;                 // n*384 + c
    const int c = plane % CCH;
    const int tid = threadIdx.x;
    const float* __restrict__ xp = x + (size_t)plane * (SP * SP);

    // --- prefetch plane into registers (HBM latency hides under LDS init) ---
    float4 stage[13];
    #pragma unroll
    for (int k = 0; k < 13; k++) {
        int i4 = tid + 64 * k;
        if (i4 < SP * SP / 4) stage[k] = ((const float4*)xp)[i4];
    }

    // --- BN fold constants (wave-uniform -> scalar loads) ---
    float S[7];
    float bias = 0.f;
    #pragma unroll
    for (int j = 0; j < 7; j++) {
        float inv = gamma[j * CCH + c] * rsqrtf(var[j * CCH + c] + 1e-5f);
        S[j] = inv;
        bias += beta[j * CCH + c] - mean[j * CCH + c] * inv;
    }

    // --- zero whole fp16 tile: 612 b128 stores ---
    {
        u32x4 z = {0u, 0u, 0u, 0u};
        #pragma unroll
        for (int k = 0; k < 10; k++) {
            int i = tid + 64 * k;
            if (i < (68 * PWH) / 8) ((u32x4*)sxh)[i] = z;
        }
    }

    // --- build merged 13x13 weights (f32, 208 slots; kx>=13 slots stay 0) ---
    #pragma unroll
    for (int k = 0; k < 4; k++) {
        int t = tid + 64 * k;
        if (t < 13 * 16) {
            int ky = t >> 4, kx = t & 15;
            float w = 0.f;
            if (kx < 13) {
                w = S[0] * w_lk[c * 169 + ky * 13 + kx];                   // 13x13 d1
                if (ky >= 4 && ky <= 8 && kx >= 4 && kx <= 8)              // 5x5 d1 @4
                    w += S[1] * w_b0[c * 25 + (ky - 4) * 5 + (kx - 4)];
                if (ky >= 3 && ky <= 9 && kx >= 3 && kx <= 9)              // 7x7 d1 @3
                    w += S[2] * w_b1[c * 49 + (ky - 3) * 7 + (kx - 3)];
                if (!(ky & 1) && !(kx & 1))                                // 7x7 d2
                    w += S[3] * w_b2[c * 49 + (ky >> 1) * 7 + (kx >> 1)];
                if (ky >= 3 && ky <= 9 && (ky - 3) % 3 == 0 &&
                    kx >= 3 && kx <= 9 && (kx - 3) % 3 == 0)               // 3x3 d3
                    w += S[4] * w_b3[c * 9 + ((ky - 3) / 3) * 3 + (kx - 3) / 3];
                if (ky >= 2 && ky <= 10 && (ky - 2) % 4 == 0 &&
                    kx >= 2 && kx <= 10 && (kx - 2) % 4 == 0)              // 3x3 d4
                    w += S[5] * w_b4[c * 9 + ((ky - 2) / 4) * 3 + (kx - 2) / 4];
                if (ky >= 1 && ky <= 11 && (ky - 1) % 5 == 0 &&
                    kx >= 1 && kx <= 11 && (kx - 1) % 5 == 0)              // 3x3 d5
                    w += S[6] * w_b5[c * 9 + ((ky - 1) / 5) * 3 + (kx - 1) / 5];
            }
            sw[t] = w;
        }
    }

    // --- pack weights to half2 pairs: swh[ky][p] = (w[2p], w[2p+1]) ---
    // slots p=0..7; p>=6 picks up the zero pad (w13..w15 = 0). Same-wave
    // LDS ordering makes the sw -> swh dependency safe without a barrier.
    #pragma unroll
    for (int k = 0; k < 2; k++) {
        int t = tid + 64 * k;
        if (t < 13 * 8) {
            int ky = t >> 3, p = t & 7;
            float w0 = sw[ky * 16 + 2 * p];
            float w1 = sw[ky * 16 + 2 * p + 1];
            hf2 hh; hh.x = (_Float16)w0; hh.y = (_Float16)w1;
            union { hf2 h; unsigned u; } cv; cv.h = hh;
            swh[t] = cv.u;
        }
    }

    // --- stage plane into LDS as fp16 (rows 6..61, data halves 8..63) ---
    #pragma unroll
    for (int k = 0; k < 13; k++) {
        int i4 = tid + 64 * k;
        if (i4 < SP * SP / 4) {
            float4 v = stage[k];
            int r = i4 / 14;                 // 14 float4 per 56-wide row
            int col = (i4 - r * 14) * 4;
            __half2* d2 = (__half2*)&sxh[(r + 6) * PWH + col + 8];
            d2[0] = __floats2half2_rn(v.x, v.y);
            d2[1] = __floats2half2_rn(v.z, v.w);
        }
    }
    __syncthreads();

    // --- compute: lane (xg,yg) -> out rows [7yg..7yg+6], cols [8xg..8xg+7] ---
    const int xg = tid & 7;
    const int yg = tid >> 3;
    const int xgc = (xg < 7) ? xg : 3;       // idle lane: broadcast with xg=3
    const int Yb = yg * 7;
    const __half* __restrict__ sbaseh = &sxh[Yb * PWH + 8 * xgc];

    float acc[7][8];
    #pragma unroll
    for (int r = 0; r < 7; r++)
        #pragma unroll
        for (int j = 0; j < 8; j++) acc[r][j] = 0.f;

    // Row load: 3 b128 -> e[0..11] (halves 0..23); odd pairs o[1..10] via
    // alignbit. Output col j tap-pair p: even j -> e[j/2+1+p], odd j ->
    // o[(j+1)/2+p]. 7 pairs cover taps 0..13 (w13=0).
#define ROWDOT(ROWP, DYN, WPA)                                              \
    {                                                                       \
        const u32x4* cp_ = (const u32x4*)(ROWP);                            \
        u32x4 c0_ = cp_[0], c1_ = cp_[1], c2_ = cp_[2];                     \
        unsigned e_[12], o_[11];                                            \
        e_[0]=c0_.x; e_[1]=c0_.y; e_[2]=c0_.z; e_[3]=c0_.w;                 \
        e_[4]=c1_.x; e_[5]=c1_.y; e_[6]=c1_.z; e_[7]=c1_.w;                 \
        e_[8]=c2_.x; e_[9]=c2_.y; e_[10]=c2_.z; e_[11]=c2_.w;               \
        _Pragma("unroll")                                                   \
        for (int t_ = 1; t_ <= 10; t_++)                                    \
            o_[t_] = (e_[t_] >> 16) | (e_[t_ + 1] << 16);                   \
        _Pragma("unroll")                                                   \
        for (int dy_ = 0; dy_ < (DYN); dy_++) {                             \
            const int r_ = i - dy_ - RBASE;                                 \
            if (r_ >= 0 && r_ < 7) {                                        \
                _Pragma("unroll")                                           \
                for (int j_ = 0; j_ < 8; j_++) {                            \
                    float a_ = acc[r_][j_];                                 \
                    _Pragma("unroll")                                       \
                    for (int p_ = 0; p_ < 7; p_++) {                        \
                        unsigned xa_ = (j_ & 1) ? o_[((j_ + 1) >> 1) + p_]  \
                                                : e_[(j_ >> 1) + 1 + p_];   \
                        a_ = dot2h(a_, xa_, WPA[dy_][p_]);                  \
                    }                                                       \
                    acc[r_][j_] = a_;                                       \
                }                                                           \
            }                                                               \
        }                                                                   \
    }

    // ky groups of 4: input rows k0..k0+9 each read ONCE, serve 4 weight rows.
    #pragma unroll 1
    for (int k0 = 0; k0 < 12; k0 += 4) {
        unsigned wp[4][7];   // wave-uniform -> SGPRs via readfirstlane
        #pragma unroll
        for (int dy = 0; dy < 4; dy++) {
            const u32x4* wr4 = (const u32x4*)&swh[(k0 + dy) * 8];
            u32x4 A = wr4[0], B = wr4[1];
            wp[dy][0] = rflu(A.x); wp[dy][1] = rflu(A.y);
            wp[dy][2] = rflu(A.z); wp[dy][3] = rflu(A.w);
            wp[dy][4] = rflu(B.x); wp[dy][5] = rflu(B.y);
            wp[dy][6] = rflu(B.z);
        }
        #define RBASE 0
        #pragma unroll
        for (int i = 0; i < 10; i++) {
            const __half* rp = sbaseh + (k0 + i) * PWH;
            // r = i - dy maps output row (within this group's local frame):
            // out row index = i - dy, valid in [0,7)
            ROWDOT(rp, 4, wp)
        }
        #undef RBASE
    }
    // tail ky = 12 (rows Yb+12..Yb+18)
    {
        unsigned wpT[1][7];
        const u32x4* wr4 = (const u32x4*)&swh[12 * 8];
        u32x4 A = wr4[0], B = wr4[1];
        wpT[0][0] = rflu(A.x); wpT[0][1] = rflu(A.y);
        wpT[0][2] = rflu(A.z); wpT[0][3] = rflu(A.w);
        wpT[0][4] = rflu(B.x); wpT[0][5] = rflu(B.y);
        wpT[0][6] = rflu(B.z);
        #define RBASE 0
        #pragma unroll
        for (int i = 0; i < 7; i++) {
            const __half* rp = sbaseh + (12 + i) * PWH;
            ROWDOT(rp, 1, wpT)
        }
        #undef RBASE
    }
#undef ROWDOT

    // --- epilogue: +bias, 2x float4 stores per row, idle col group masked ---
    if (xg < 7) {
        float* op = out + (size_t)plane * (SP * SP) + Yb * SP + 8 * xg;
        #pragma unroll
        for (int r = 0; r < 7; r++) {
            float4 v0 = make_float4(acc[r][0] + bias, acc[r][1] + bias,
                                    acc[r][2] + bias, acc[r][3] + bias);
            float4 v1 = make_float4(acc[r][4] + bias, acc[r][5] + bias,
                                    acc[r][6] + bias, acc[r][7] + bias);
            *(float4*)(op + r * SP) = v0;
            *(float4*)(op + r * SP + 4) = v1;
        }
    }
}

extern "C" void kernel_launch(void* const* d_in, const int* in_sizes, int n_in,
                              void* d_out, int out_size, void* d_ws, size_t ws_size,
                              hipStream_t stream) {
    const float* x    = (const float*)d_in[0];
    const float* w_lk = (const float*)d_in[1];
    const float* w_b0 = (const float*)d_in[2];
    const float* w_b1 = (const float*)d_in[3];
    const float* w_b2 = (const float*)d_in[4];
    const float* w_b3 = (const float*)d_in[5];
    const float* w_b4 = (const float*)d_in[6];
    const float* w_b5 = (const float*)d_in[7];
    const float* bn_g = (const float*)d_in[8];
    const float* bn_b = (const float*)d_in[9];
    const float* bn_m = (const float*)d_in[10];
    const float* bn_v = (const float*)d_in[11];
    float* out = (float*)d_out;

    drb_conv13_r14<<<dim3(NPLANES), dim3(64), 0, stream>>>(
        x, w_lk, w_b0, w_b1, w_b2, w_b3, w_b4, w_b5,
        bn_g, bn_b, bn_m, bn_v, out);
}

// Round 12
// 227.493 us; speedup vs baseline: 1.0159x; 1.0159x over previous
//
#include <hip/hip_runtime.h>
#include <hip/hip_fp16.h>

// DilatedReparamBlock folded into one 13x13 depthwise conv + bias.
//
// R15: full-rate packed-fp16 FMA. R14 post-mortem: back-solved cycle model
// shows v_dot2_f32_f16 is HALF-RATE on gfx950 (4 cyc/wave64, same MAC/cyc
// as v_fmac_f32); R14's win was killing the cvt chain. The only full-rate
// 2-MAC path is v_pk_fma_f16 (2x fp32 rate).
//  - inner loop: output col-PAIRS accumulated as __half2 via __hfma2;
//    x-pairs for any alignment come free from the existing e_/o_ arrays;
//    weights as broadcast (w,w) half2 -> 52 u32/group via readfirstlane.
//  - pk_fma count 13*7*4*13 = 4732 @2cyc ~ 9.5k cyc vs dot2 20.4k.
//  - fp16 partial limited to one ky-group (<=52 taps), folded to f32 acc
//    per group (+~2e-3 err; fallback = per-ky fold if absmax fails).
//  - s_setprio(1) around compute (T5: independent 1-wave blocks).
//  - else R14: fp16 LDS plane (3 b128/row), ky-groups of 4 + tail,
//    64 thr / 7x8 lane tiles, register plane prefetch.

#define CCH 384
#define SP 56
#define PWH 72             // halves per padded row (16B-aligned lane bases)
#define NPLANES (16*384)

typedef __attribute__((ext_vector_type(4))) unsigned int u32x4;

__device__ __forceinline__ unsigned rflu(unsigned v) {
    return (unsigned)__builtin_amdgcn_readfirstlane((int)v);
}
__device__ __forceinline__ __half2 h2(unsigned v) {
    union { unsigned u; __half2 h; } x; x.u = v; return x.h;
}
__device__ __forceinline__ unsigned uh(__half2 h) {
    union { __half2 h; unsigned u; } x; x.h = h; return x.u;
}

__global__ __launch_bounds__(64, 2) void drb_conv13_r15(
    const float* __restrict__ x,
    const float* __restrict__ w_lk, const float* __restrict__ w_b0,
    const float* __restrict__ w_b1, const float* __restrict__ w_b2,
    const float* __restrict__ w_b3, const float* __restrict__ w_b4,
    const float* __restrict__ w_b5,
    const float* __restrict__ gamma, const float* __restrict__ beta,
    const float* __restrict__ mean, const float* __restrict__ var,
    float* __restrict__ out)
{
    __shared__ __align__(16) __half sxh[68 * PWH];    // 9792 B fp16 plane
    __shared__ __align__(16) float sw[13 * 16];       // merged weights, f32
    __shared__ __align__(16) unsigned swb[13 * 16];   // (w,w) half2 pairs

    const int plane = blockIdx.x;                 // n*384 + c
    const int c = plane % CCH;
    const int tid = threadIdx.x;
    const float* __restrict__ xp = x + (size_t)plane * (SP * SP);

    // --- prefetch plane into registers (HBM latency hides under LDS init) ---
    float4 stage[13];
    #pragma unroll
    for (int k = 0; k < 13; k++) {
        int i4 = tid + 64 * k;
        if (i4 < SP * SP / 4) stage[k] = ((const float4*)xp)[i4];
    }

    // --- BN fold constants (wave-uniform -> scalar loads) ---
    float S[7];
    float bias = 0.f;
    #pragma unroll
    for (int j = 0; j < 7; j++) {
        float inv = gamma[j * CCH + c] * rsqrtf(var[j * CCH + c] + 1e-5f);
        S[j] = inv;
        bias += beta[j * CCH + c] - mean[j * CCH + c] * inv;
    }

    // --- zero whole fp16 tile: 612 b128 stores ---
    {
        u32x4 z = {0u, 0u, 0u, 0u};
        #pragma unroll
        for (int k = 0; k < 10; k++) {
            int i = tid + 64 * k;
            if (i < (68 * PWH) / 8) ((u32x4*)sxh)[i] = z;
        }
    }

    // --- build merged 13x13 weights (f32; kx>=13 slots stay 0) ---
    #pragma unroll
    for (int k = 0; k < 4; k++) {
        int t = tid + 64 * k;
        if (t < 13 * 16) {
            int ky = t >> 4, kx = t & 15;
            float w = 0.f;
            if (kx < 13) {
                w = S[0] * w_lk[c * 169 + ky * 13 + kx];                   // 13x13 d1
                if (ky >= 4 && ky <= 8 && kx >= 4 && kx <= 8)              // 5x5 d1 @4
                    w += S[1] * w_b0[c * 25 + (ky - 4) * 5 + (kx - 4)];
                if (ky >= 3 && ky <= 9 && kx >= 3 && kx <= 9)              // 7x7 d1 @3
                    w += S[2] * w_b1[c * 49 + (ky - 3) * 7 + (kx - 3)];
                if (!(ky & 1) && !(kx & 1))                                // 7x7 d2
                    w += S[3] * w_b2[c * 49 + (ky >> 1) * 7 + (kx >> 1)];
                if (ky >= 3 && ky <= 9 && (ky - 3) % 3 == 0 &&
                    kx >= 3 && kx <= 9 && (kx - 3) % 3 == 0)               // 3x3 d3
                    w += S[4] * w_b3[c * 9 + ((ky - 3) / 3) * 3 + (kx - 3) / 3];
                if (ky >= 2 && ky <= 10 && (ky - 2) % 4 == 0 &&
                    kx >= 2 && kx <= 10 && (kx - 2) % 4 == 0)              // 3x3 d4
                    w += S[5] * w_b4[c * 9 + ((ky - 2) / 4) * 3 + (kx - 2) / 4];
                if (ky >= 1 && ky <= 11 && (ky - 1) % 5 == 0 &&
                    kx >= 1 && kx <= 11 && (kx - 1) % 5 == 0)              // 3x3 d5
                    w += S[6] * w_b5[c * 9 + ((ky - 1) / 5) * 3 + (kx - 1) / 5];
            }
            sw[t] = w;
        }
    }

    // --- pack broadcast pairs swb[ky*16+kx] = (w,w) as half2 ---
    // same-wave LDS ordering makes sw -> swb safe without a barrier
    #pragma unroll
    for (int k = 0; k < 4; k++) {
        int t = tid + 64 * k;
        if (t < 13 * 16) {
            float w = sw[t];
            swb[t] = uh(__floats2half2_rn(w, w));
        }
    }

    // --- stage plane into LDS as fp16 (rows 6..61, data halves 8..63) ---
    #pragma unroll
    for (int k = 0; k < 13; k++) {
        int i4 = tid + 64 * k;
        if (i4 < SP * SP / 4) {
            float4 v = stage[k];
            int r = i4 / 14;                 // 14 float4 per 56-wide row
            int col = (i4 - r * 14) * 4;
            __half2* d2 = (__half2*)&sxh[(r + 6) * PWH + col + 8];
            d2[0] = __floats2half2_rn(v.x, v.y);
            d2[1] = __floats2half2_rn(v.z, v.w);
        }
    }
    __syncthreads();
    __builtin_amdgcn_s_setprio(1);

    // --- compute: lane (xg,yg) -> out rows [7yg..7yg+6], cols [8xg..8xg+7] ---
    const int xg = tid & 7;
    const int yg = tid >> 3;
    const int xgc = (xg < 7) ? xg : 3;       // idle lane: broadcast with xg=3
    const int Yb = yg * 7;
    const __half* __restrict__ sbaseh = &sxh[Yb * PWH + 8 * xgc];

    float acc[7][8];
    #pragma unroll
    for (int r = 0; r < 7; r++)
        #pragma unroll
        for (int j = 0; j < 8; j++) acc[r][j] = 0.f;

    // Row window: e_[t] = halves (2t,2t+1); o_[t] = halves (2t+1,2t+2).
    // Half index for (output col j, tap kx) = j + 2 + kx. Col-pair (2cp):
    //   even kx -> e_[cp + 1 + kx/2]; odd kx -> o_[cp + (kx+1)/2].
#define ROWPK(ROWP, DYN)                                                    \
    {                                                                       \
        const u32x4* cp4_ = (const u32x4*)(ROWP);                           \
        u32x4 c0_ = cp4_[0], c1_ = cp4_[1], c2_ = cp4_[2];                  \
        unsigned e_[12], o_[10];                                            \
        e_[0]=c0_.x; e_[1]=c0_.y; e_[2]=c0_.z; e_[3]=c0_.w;                 \
        e_[4]=c1_.x; e_[5]=c1_.y; e_[6]=c1_.z; e_[7]=c1_.w;                 \
        e_[8]=c2_.x; e_[9]=c2_.y; e_[10]=c2_.z; e_[11]=c2_.w;               \
        _Pragma("unroll")                                                   \
        for (int t_ = 1; t_ <= 9; t_++)                                     \
            o_[t_] = (e_[t_] >> 16) | (e_[t_ + 1] << 16);                   \
        _Pragma("unroll")                                                   \
        for (int dy_ = 0; dy_ < (DYN); dy_++) {                             \
            const int r_ = i - dy_;                                         \
            if (r_ >= 0 && r_ < 7) {                                        \
                _Pragma("unroll")                                           \
                for (int cp_ = 0; cp_ < 4; cp_++) {                         \
                    __half2 hs_ = hacc[r_][cp_];                            \
                    _Pragma("unroll")                                       \
                    for (int kx_ = 0; kx_ < 13; kx_++) {                    \
                        unsigned xa_ = (kx_ & 1) ? o_[cp_ + ((kx_ + 1) >> 1)] \
                                                 : e_[cp_ + 1 + (kx_ >> 1)]; \
                        hs_ = __hfma2(h2(xa_), h2(wbc[dy_][kx_]), hs_);     \
                    }                                                       \
                    hacc[r_][cp_] = hs_;                                    \
                }                                                           \
            }                                                               \
        }                                                                   \
    }

    // ky groups of 4: input rows k0..k0+9 each read ONCE, serve 4 weight
    // rows; fp16 partials per group, folded to f32 acc at group end.
    #pragma unroll 1
    for (int k0 = 0; k0 < 12; k0 += 4) {
        unsigned wbc[4][13];   // wave-uniform -> SGPRs via readfirstlane
        #pragma unroll
        for (int dy = 0; dy < 4; dy++) {
            const u32x4* wr4 = (const u32x4*)&swb[(k0 + dy) * 16];
            u32x4 A = wr4[0], B = wr4[1], C = wr4[2];
            wbc[dy][0] = rflu(A.x); wbc[dy][1] = rflu(A.y);
            wbc[dy][2] = rflu(A.z); wbc[dy][3] = rflu(A.w);
            wbc[dy][4] = rflu(B.x); wbc[dy][5] = rflu(B.y);
            wbc[dy][6] = rflu(B.z); wbc[dy][7] = rflu(B.w);
            wbc[dy][8] = rflu(C.x); wbc[dy][9] = rflu(C.y);
            wbc[dy][10] = rflu(C.z); wbc[dy][11] = rflu(C.w);
            wbc[dy][12] = rflu(((const unsigned*)&swb[(k0 + dy) * 16])[12]);
        }
        __half2 hacc[7][4];
        #pragma unroll
        for (int r = 0; r < 7; r++)
            #pragma unroll
            for (int q = 0; q < 4; q++) hacc[r][q] = h2(0u);
        #pragma unroll
        for (int i = 0; i < 10; i++) {
            const __half* rp = sbaseh + (k0 + i) * PWH;
            ROWPK(rp, 4)
        }
        // fold fp16 group partials into f32 accumulators
        #pragma unroll
        for (int r = 0; r < 7; r++)
            #pragma unroll
            for (int q = 0; q < 4; q++) {
                float2 f = __half22float2(hacc[r][q]);
                acc[r][2 * q]     += f.x;
                acc[r][2 * q + 1] += f.y;
            }
    }
    // tail ky = 12 (rows Yb+12..Yb+18)
    {
        unsigned wbc[1][13];
        const u32x4* wr4 = (const u32x4*)&swb[12 * 16];
        u32x4 A = wr4[0], B = wr4[1], C = wr4[2];
        wbc[0][0] = rflu(A.x); wbc[0][1] = rflu(A.y);
        wbc[0][2] = rflu(A.z); wbc[0][3] = rflu(A.w);
        wbc[0][4] = rflu(B.x); wbc[0][5] = rflu(B.y);
        wbc[0][6] = rflu(B.z); wbc[0][7] = rflu(B.w);
        wbc[0][8] = rflu(C.x); wbc[0][9] = rflu(C.y);
        wbc[0][10] = rflu(C.z); wbc[0][11] = rflu(C.w);
        wbc[0][12] = rflu(((const unsigned*)&swb[12 * 16])[12]);
        __half2 hacc[7][4];
        #pragma unroll
        for (int r = 0; r < 7; r++)
            #pragma unroll
            for (int q = 0; q < 4; q++) hacc[r][q] = h2(0u);
        #pragma unroll
        for (int ii = 0; ii < 7; ii++) {
            const int i = ii;   // r_ = i - 0
            const __half* rp = sbaseh + (12 + ii) * PWH;
            ROWPK(rp, 1)
        }
        #pragma unroll
        for (int r = 0; r < 7; r++)
            #pragma unroll
            for (int q = 0; q < 4; q++) {
                float2 f = __half22float2(hacc[r][q]);
                acc[r][2 * q]     += f.x;
                acc[r][2 * q + 1] += f.y;
            }
    }
#undef ROWPK
    __builtin_amdgcn_s_setprio(0);

    // --- epilogue: +bias, 2x float4 stores per row, idle col group masked ---
    if (xg < 7) {
        float* op = out + (size_t)plane * (SP * SP) + Yb * SP + 8 * xg;
        #pragma unroll
        for (int r = 0; r < 7; r++) {
            float4 v0 = make_float4(acc[r][0] + bias, acc[r][1] + bias,
                                    acc[r][2] + bias, acc[r][3] + bias);
            float4 v1 = make_float4(acc[r][4] + bias, acc[r][5] + bias,
                                    acc[r][6] + bias, acc[r][7] + bias);
            *(float4*)(op + r * SP) = v0;
            *(float4*)(op + r * SP + 4) = v1;
        }
    }
}

extern "C" void kernel_launch(void* const* d_in, const int* in_sizes, int n_in,
                              void* d_out, int out_size, void* d_ws, size_t ws_size,
                              hipStream_t stream) {
    const float* x    = (const float*)d_in[0];
    const float* w_lk = (const float*)d_in[1];
    const float* w_b0 = (const float*)d_in[2];
    const float* w_b1 = (const float*)d_in[3];
    const float* w_b2 = (const float*)d_in[4];
    const float* w_b3 = (const float*)d_in[5];
    const float* w_b4 = (const float*)d_in[6];
    const float* w_b5 = (const float*)d_in[7];
    const float* bn_g = (const float*)d_in[8];
    const float* bn_b = (const float*)d_in[9];
    const float* bn_m = (const float*)d_in[10];
    const float* bn_v = (const float*)d_in[11];
    float* out = (float*)d_out;

    drb_conv13_r15<<<dim3(NPLANES), dim3(64), 0, stream>>>(
        x, w_lk, w_b0, w_b1, w_b2, w_b3, w_b4, w_b5,
        bn_g, bn_b, bn_m, bn_v, out);
}